// Round 9
// baseline (335.348 us; speedup 1.0000x reference)
//
#include <hip/hip_runtime.h>
#include <stdint.h>
#include <utility>

// ---------------- problem constants ----------------
#define NPTS   262144      // 4 * 65536
#define GXGY   140800      // 352*400
#define GYv    400
#define NSEG   563201      // 4*GXGY + 1
#define SENT   563200
#define NB_SCAN 275        // 563200 / 2048
#define PIL_BLOCKS 2048    // persistent k_pillar grid
#define MOM_BLOCKS 1024

// ---------------- ws layout (bytes); total ~34 MB ----------------
constexpr size_t alignup(size_t x) { return (x + 255) & ~(size_t)255; }
constexpr size_t O_CNT  = 0;                                   // NSEG u32 (zeroed)
constexpr size_t O_SUMS = alignup(O_CNT + (size_t)NSEG * 4);   // NSEG*3 f32 (zeroed)
constexpr size_t O_MOM  = alignup(O_SUMS + (size_t)NSEG * 12); // 104 f32 (zeroed)
constexpr size_t O_DONE = alignup(O_MOM + 104 * 4);            // 1 u32 ticket (zeroed)
constexpr size_t ZERO_BYTES = alignup(O_DONE + 4);
constexpr size_t O_PPTR = ZERO_BYTES;                          // NSEG u32 (sort cursor)
constexpr size_t O_LINA = alignup(O_PPTR + (size_t)NSEG * 4);  // NPTS u32 (per-point lin)
constexpr size_t O_ROWI = alignup(O_LINA + (size_t)NPTS * 4);  // NPTS uint4 (rank -> id,start,n)
constexpr size_t O_FEAT = alignup(O_ROWI + (size_t)NPTS * 16); // NPTS*16 f32 (sorted feats)
constexpr size_t O_BSO  = alignup(O_FEAT + (size_t)NPTS * 64); // NB_SCAN u32 occ block sums
constexpr size_t O_BSC  = alignup(O_BSO + NB_SCAN * 4);        // NB_SCAN u32 cnt block sums
constexpr size_t O_KP   = alignup(O_BSC + NB_SCAN * 4);        // 1 u32 (#real pillars)
constexpr size_t O_WF   = alignup(O_KP + 256);                 // 832 f32: W*scale folded
constexpr size_t O_SH   = alignup(O_WF + 832 * 4);             // 64 f32: shift

// binning: mirror reference f32 arithmetic exactly (division, trunc, compares)
__device__ __forceinline__ int point_lin(float x, float y, int b, bool& mask) {
  float cxf = x / 0.2f;
  float cyf = (y + 40.0f) / 0.2f;
  int cx = (int)cxf, cy = (int)cyf;
  mask = (cxf >= 0.0f) && (cxf < 352.0f) && (cyf >= 0.0f) && (cyf < 400.0f);
  return mask ? (b * GXGY + cx * GYv + cy) : SENT;
}

// ---------------- K1: count + xyz sums + lin cache ----------------
__global__ __launch_bounds__(256) void k_count(const float* __restrict__ pts,
                                               unsigned int* __restrict__ cnt,
                                               float* __restrict__ sums,
                                               unsigned int* __restrict__ lina) {
  int i = blockIdx.x * 256 + threadIdx.x;
  if (i >= NPTS) return;
  const float* p = pts + (size_t)i * 7;
  float x = p[0], y = p[1], z = p[2];
  bool m;
  int lin = point_lin(x, y, i >> 16, m);
  lina[i] = (unsigned)lin;
  atomicAdd(&cnt[lin], 1u);
  atomicAdd(&sums[lin * 3 + 0], x);
  atomicAdd(&sums[lin * 3 + 1], y);
  atomicAdd(&sums[lin * 3 + 2], z);
}

// ---------------- K2: per-block occupancy/count sums ----------------
__global__ __launch_bounds__(256) void k_scan1(const unsigned int* __restrict__ cnt,
                                               unsigned int* __restrict__ bso,
                                               unsigned int* __restrict__ bsc) {
  int t = threadIdx.x;
  int base = blockIdx.x * 2048 + t * 8;
  const uint4* c4 = (const uint4*)(cnt + base);
  uint4 a = c4[0], b = c4[1];
  unsigned so = (a.x > 0) + (a.y > 0) + (a.z > 0) + (a.w > 0) +
                (b.x > 0) + (b.y > 0) + (b.z > 0) + (b.w > 0);
  unsigned sc = a.x + a.y + a.z + a.w + b.x + b.y + b.z + b.w;
  for (int m = 1; m < 64; m <<= 1) { so += __shfl_xor(so, m); sc += __shfl_xor(sc, m); }
  __shared__ unsigned wo[4], wc[4];
  if ((t & 63) == 0) { wo[t >> 6] = so; wc[t >> 6] = sc; }
  __syncthreads();
  if (t == 0) {
    bso[blockIdx.x] = wo[0] + wo[1] + wo[2] + wo[3];
    bsc[blockIdx.x] = wc[0] + wc[1] + wc[2] + wc[3];
  }
}

// ---------------- K3: ranks + rowinfo + sort-cursor (self-computed block offsets) ----------------
__global__ __launch_bounds__(256) void k_scan3(const unsigned int* __restrict__ cnt,
                                               const unsigned int* __restrict__ bso,
                                               const unsigned int* __restrict__ bsc,
                                               uint4* __restrict__ rowinfo,
                                               unsigned int* __restrict__ pptr,
                                               unsigned int* __restrict__ kp) {
  int t = threadIdx.x;
  // block offsets: reduce per-block sums below blockIdx.x (and total occ for kp)
  // NB_SCAN (275) > blockDim (256): strided loop covers all entries.
  unsigned vo_m = 0, vc_m = 0, vo_a = 0;
  for (int e = t; e < NB_SCAN; e += 256) {
    unsigned o = bso[e], c = bsc[e];
    vo_a += o;
    if (e < (int)blockIdx.x) { vo_m += o; vc_m += c; }
  }
  for (int m = 1; m < 64; m <<= 1) {
    vo_m += __shfl_xor(vo_m, m);
    vc_m += __shfl_xor(vc_m, m);
    vo_a += __shfl_xor(vo_a, m);
  }
  __shared__ unsigned s0[4], s1[4], s2[4];
  int wv = t >> 6;
  if ((t & 63) == 0) { s0[wv] = vo_m; s1[wv] = vc_m; s2[wv] = vo_a; }
  __syncthreads();
  unsigned boo = s0[0] + s0[1] + s0[2] + s0[3];
  unsigned boc = s1[0] + s1[1] + s1[2] + s1[3];
  unsigned tot = s2[0] + s2[1] + s2[2] + s2[3];
  if (blockIdx.x == 0 && t == 0) *kp = tot;

  int base = blockIdx.x * 2048 + t * 8;
  const uint4* q = (const uint4*)(cnt + base);
  uint4 a = q[0], b = q[1];
  unsigned c[8] = {a.x, a.y, a.z, a.w, b.x, b.y, b.z, b.w};
  unsigned po[8], pc[8];
  unsigned so = 0, sc = 0;
#pragma unroll
  for (int k = 0; k < 8; k++) {
    po[k] = so; pc[k] = sc;
    so += (c[k] > 0); sc += c[k];
  }
  __shared__ unsigned sdo[256], sdc[256];
  __syncthreads();
  sdo[t] = so; sdc[t] = sc;
  __syncthreads();
  for (int off = 1; off < 256; off <<= 1) {
    unsigned ao = (t >= off) ? sdo[t - off] : 0u;
    unsigned ac = (t >= off) ? sdc[t - off] : 0u;
    __syncthreads();
    sdo[t] += ao; sdc[t] += ac;
    __syncthreads();
  }
  unsigned eo = sdo[t] - so + boo;
  unsigned ec = sdc[t] - sc + boc;
#pragma unroll
  for (int k = 0; k < 8; k++) {
    if (c[k] > 0) {
      unsigned r = eo + po[k];
      unsigned start = ec + pc[k];
      rowinfo[r] = make_uint4((unsigned)(base + k), start, c[k], 0u);
      pptr[base + k] = start;   // exclusive start; sortfeat advances to start+n
    }
  }
}

// ---------------- K4: counting-sort + feature materialization ----------------
__global__ __launch_bounds__(256) void k_sortfeat(const float* __restrict__ pts,
                                                  const unsigned int* __restrict__ lina,
                                                  const unsigned int* __restrict__ cnt,
                                                  const float* __restrict__ sums,
                                                  unsigned int* __restrict__ pptr,
                                                  float* __restrict__ feat) {
  int i = blockIdx.x * 256 + threadIdx.x;
  if (i >= NPTS) return;
  unsigned lin = lina[i];
  if (lin == SENT) return;  // masked points never reach output rows
  const float* p = pts + (size_t)i * 7;
  float x = p[0], y = p[1], z = p[2];
  unsigned pos = atomicAdd(&pptr[lin], 1u);
  float cm = fmaxf((float)cnt[lin], 1.0f);
  float m0 = sums[lin * 3 + 0] / cm;
  float m1 = sums[lin * 3 + 1] / cm;
  float m2 = sums[lin * 3 + 2] / cm;
  int cx = (int)(x / 0.2f);
  int cy = (int)((y + 40.0f) / 0.2f);
  int cz = (int)((z + 3.0f) / 4.0f);
  float4 A = make_float4(x, y, z, p[3]);
  float4 B = make_float4(p[4], p[5], p[6], x - m0);
  float4 C = make_float4(y - m1, z - m2,
                         x - ((float)cx * 0.2f + 0.1f + 0.0f),
                         y - ((float)cy * 0.2f + 0.1f - 40.0f));
  float4 D = make_float4(z - ((float)cz * 4.0f + 2.0f - 3.0f), 0.f, 0.f, 0.f);
  float4* fb = (float4*)(feat + (size_t)pos * 16);
  fb[0] = A; fb[1] = B; fb[2] = C; fb[3] = D;
}

// ---------------- K5: feature moments + fused BN finalize ----------------
// x = F W^T  =>  mu = W*E[f],  E[x_c^2] = w_c E[f f^T] w_c^T
constexpr int tri_j(int t) { int j = 0; while (t >= 13 - j) { t -= 13 - j; j++; } return j; }
constexpr int tri_k(int t) { int j = 0; while (t >= 13 - j) { t -= 13 - j; j++; } return j + t; }

template<int G, size_t U>
__device__ __forceinline__ void accum_one(const float (&f)[13], float (&acc)[52]) {
  constexpr int E = G * 52 + (int)U;
  if constexpr (E < 13) {
    acc[U] += f[E];
  } else {
    constexpr int J = tri_j(E - 13);
    constexpr int K = tri_k(E - 13);
    acc[U] += f[J] * f[K];
  }
}
template<int G, size_t... Us>
__device__ __forceinline__ void accum_all(const float (&f)[13], float (&acc)[52],
                                          std::index_sequence<Us...>) {
  (accum_one<G, Us>(f, acc), ...);
}

template<int G>
__device__ __forceinline__ void moments_body(const float* __restrict__ feat,
                                             float* __restrict__ mom, int chunk) {
  float acc[52];
#pragma unroll
  for (int u = 0; u < 52; u++) acc[u] = 0.f;
#pragma unroll
  for (int r = 0; r < 4; r++) {
    int i = chunk * 1024 + r * 256 + threadIdx.x;
    const float4* fp = (const float4*)(feat + (size_t)i * 16);
    float4 A = fp[0], B = fp[1], C = fp[2], D = fp[3];
    float f[13] = {A.x, A.y, A.z, A.w, B.x, B.y, B.z, B.w, C.x, C.y, C.z, C.w, D.x};
    accum_all<G>(f, acc, std::make_index_sequence<52>{});
  }
  __shared__ float red[4][52];
  int wv = threadIdx.x >> 6, lane = threadIdx.x & 63;
#pragma unroll
  for (int u = 0; u < 52; u++) {
    float v = acc[u];
    v += __shfl_xor(v, 1);  v += __shfl_xor(v, 2);  v += __shfl_xor(v, 4);
    v += __shfl_xor(v, 8);  v += __shfl_xor(v, 16); v += __shfl_xor(v, 32);
    if (lane == 0) red[wv][u] = v;
  }
  __syncthreads();
  if (threadIdx.x < 52) {
    int u = threadIdx.x;
    atomicAdd(&mom[G * 52 + u], red[0][u] + red[1][u] + red[2][u] + red[3][u]);
  }
}

__global__ __launch_bounds__(256, 2) void k_moments(const float* __restrict__ feat,
                                                    float* __restrict__ mom,
                                                    unsigned int* __restrict__ done,
                                                    const float* __restrict__ W,
                                                    const float* __restrict__ g,
                                                    const float* __restrict__ bta,
                                                    float* __restrict__ wf,
                                                    float* __restrict__ sh) {
  int chunk = blockIdx.x >> 1;     // 256 chunks x 1024 points
  if ((blockIdx.x & 1) == 0) moments_body<0>(feat, mom, chunk);
  else                       moments_body<1>(feat, mom, chunk);

  // last block folds BN into W (device-scope ticket; atomic re-read of mom)
  __threadfence();
  __shared__ unsigned lastFlag;
  if (threadIdx.x == 0)
    lastFlag = (atomicAdd(done, 1u) == (unsigned)(gridDim.x - 1)) ? 1u : 0u;
  __syncthreads();
  if (!lastFlag) return;

  __shared__ float lm[104];
  int t = threadIdx.x;
  if (t < 104) lm[t] = atomicAdd(&mom[t], 0.0f);  // coherent read
  __syncthreads();
  if (t < 64) {
    float w[13];
#pragma unroll
    for (int j = 0; j < 13; j++) w[j] = W[t * 13 + j];
    const float invN = 1.0f / (float)NPTS;
    float mu = 0.f;
#pragma unroll
    for (int j = 0; j < 13; j++) mu += w[j] * (lm[j] * invN);
    float e2 = 0.f;
    int mi = 13;
#pragma unroll
    for (int j = 0; j < 13; j++) {
#pragma unroll
      for (int k = j; k < 13; k++) {
        float coef = (j == k) ? 1.0f : 2.0f;
        e2 += coef * w[j] * w[k] * lm[mi];
        mi++;
      }
    }
    e2 *= invN;
    float var = e2 - mu * mu;
    float rsig = 1.0f / sqrtf(var + 1e-3f);
    float sc = g[t] * rsig;
#pragma unroll
    for (int j = 0; j < 13; j++) wf[t * 13 + j] = w[j] * sc;
    sh[t] = bta[t] - mu * sc;
  }
}

// ---------------- K6: persistent per-pillar PFN + max + full output ----------------
// rowinfo gives (id,start,n) in ONE coalesced load; feat reads are sequential
// in rank order. Weights in 52 VGPRs per lane, loaded once per thread.
__global__ __launch_bounds__(256) void k_pillar(const float* __restrict__ wf,
                                                const float* __restrict__ sh,
                                                const uint4* __restrict__ rowinfo,
                                                const unsigned int* __restrict__ kp_p,
                                                const float* __restrict__ feat,
                                                float* __restrict__ out) {
  int tid = threadIdx.x;
  int lane = tid & 15;
  int ch0 = lane * 4;
  float wr[52];
  float shv[4];
#pragma unroll
  for (int c4 = 0; c4 < 4; c4++) {
    shv[c4] = sh[ch0 + c4];
#pragma unroll
    for (int j = 0; j < 13; j++) wr[c4 * 13 + j] = wf[(ch0 + c4) * 13 + j];
  }
  unsigned kp = *kp_p;

  const int NGRP = PIL_BLOCKS * 16;
  for (int r = blockIdx.x * 16 + (tid >> 4); r < NSEG; r += NGRP) {
    float m0 = -3.4e38f, m1 = -3.4e38f, m2 = -3.4e38f, m3 = -3.4e38f;
    int b = 4, cy = 0, cx = 0;
    if ((unsigned)r < kp) {
      uint4 ri = rowinfo[r];
      unsigned id = ri.x, start = ri.y, n = ri.z;
      b = id / GXGY;
      unsigned rem = id - (unsigned)b * GXGY;
      cx = rem / GYv;
      cy = rem - cx * GYv;
      const float4* fb = (const float4*)(feat + (size_t)start * 16);
      for (unsigned p = 0; p < n; p++) {
        float4 A = fb[0], B = fb[1], C = fb[2], D = fb[3];
        fb += 4;
        float d0, d1, d2, d3;
#define DOT(dst, c4)                                                          \
        dst = shv[c4];                                                        \
        dst += wr[c4 * 13 + 0]  * A.x;  dst += wr[c4 * 13 + 1]  * A.y;        \
        dst += wr[c4 * 13 + 2]  * A.z;  dst += wr[c4 * 13 + 3]  * A.w;        \
        dst += wr[c4 * 13 + 4]  * B.x;  dst += wr[c4 * 13 + 5]  * B.y;        \
        dst += wr[c4 * 13 + 6]  * B.z;  dst += wr[c4 * 13 + 7]  * B.w;        \
        dst += wr[c4 * 13 + 8]  * C.x;  dst += wr[c4 * 13 + 9]  * C.y;        \
        dst += wr[c4 * 13 + 10] * C.z;  dst += wr[c4 * 13 + 11] * C.w;        \
        dst += wr[c4 * 13 + 12] * D.x;
        DOT(d0, 0) DOT(d1, 1) DOT(d2, 2) DOT(d3, 3)
#undef DOT
        m0 = fmaxf(m0, d0); m1 = fmaxf(m1, d1);
        m2 = fmaxf(m2, d2); m3 = fmaxf(m3, d3);
      }
    }
    float4 v = make_float4(fmaxf(m0, 0.f), fmaxf(m1, 0.f),
                           fmaxf(m2, 0.f), fmaxf(m3, 0.f));
    *(float4*)(out + (size_t)r * 64 + lane * 4) = v;
    if (lane == 0) {
      float* cc = out + (size_t)NSEG * 64 + (size_t)r * 3;
      cc[0] = (float)b;
      cc[1] = (float)cy;
      cc[2] = (float)cx;
    }
  }
  if (blockIdx.x == 0 && tid == 0) {
    float* g = out + (size_t)NSEG * 67;
    g[0] = 400.0f;  // GY
    g[1] = 352.0f;  // GX
  }
}

// ---------------- host launcher ----------------
extern "C" void kernel_launch(void* const* d_in, const int* in_sizes, int n_in,
                              void* d_out, int out_size, void* d_ws, size_t ws_size,
                              hipStream_t stream) {
  const float* pts = (const float*)d_in[0];
  const float* W   = (const float*)d_in[1];
  const float* g   = (const float*)d_in[2];
  const float* bta = (const float*)d_in[3];
  float* out = (float*)d_out;
  char* ws = (char*)d_ws;

  unsigned int* cnt  = (unsigned int*)(ws + O_CNT);
  float*        sums = (float*)(ws + O_SUMS);
  float*        mom  = (float*)(ws + O_MOM);
  unsigned int* done = (unsigned int*)(ws + O_DONE);
  unsigned int* pptr = (unsigned int*)(ws + O_PPTR);
  unsigned int* lina = (unsigned int*)(ws + O_LINA);
  uint4*        rowi = (uint4*)(ws + O_ROWI);
  float*        feat = (float*)(ws + O_FEAT);
  unsigned int* bso  = (unsigned int*)(ws + O_BSO);
  unsigned int* bsc  = (unsigned int*)(ws + O_BSC);
  unsigned int* kp   = (unsigned int*)(ws + O_KP);
  float*        wf   = (float*)(ws + O_WF);
  float*        sh   = (float*)(ws + O_SH);
  (void)in_sizes; (void)n_in; (void)out_size; (void)ws_size;

  hipMemsetAsync(ws, 0, ZERO_BYTES, stream);   // cnt + sums + moments + ticket

  k_count   <<<NPTS / 256, 256, 0, stream>>>(pts, cnt, sums, lina);
  k_scan1   <<<NB_SCAN, 256, 0, stream>>>(cnt, bso, bsc);
  k_scan3   <<<NB_SCAN, 256, 0, stream>>>(cnt, bso, bsc, rowi, pptr, kp);
  k_sortfeat<<<NPTS / 256, 256, 0, stream>>>(pts, lina, cnt, sums, pptr, feat);
  k_moments <<<MOM_BLOCKS, 256, 0, stream>>>(feat, mom, done, W, g, bta, wf, sh);
  k_pillar  <<<PIL_BLOCKS, 256, 0, stream>>>(wf, sh, rowi, kp, feat, out);
}

// Round 10
// 287.888 us; speedup vs baseline: 1.1649x; 1.1649x over previous
//
#include <hip/hip_runtime.h>
#include <stdint.h>
#include <utility>

// ---------------- problem constants ----------------
#define NPTS   262144      // 4 * 65536
#define GXGY   140800      // 352*400
#define GYv    400
#define NSEG   563201      // 4*GXGY + 1
#define SENT   563200
#define NB_SCAN 275        // 563200 / 2048
#define PIL_BLOCKS 2048    // persistent k_pillar grid
#define MOM_BLOCKS 512     // 2 groups x 256 chunks (1024 points each) == NPTS exactly

// ---------------- ws layout (bytes); total ~34 MB ----------------
constexpr size_t alignup(size_t x) { return (x + 255) & ~(size_t)255; }
constexpr size_t O_CNT  = 0;                                   // NSEG u32 (zeroed)
constexpr size_t O_SUMS = alignup(O_CNT + (size_t)NSEG * 4);   // NSEG*3 f32 (zeroed)
constexpr size_t O_MOM  = alignup(O_SUMS + (size_t)NSEG * 12); // 104 f32 (zeroed)
constexpr size_t ZERO_BYTES = alignup(O_MOM + 104 * 4);
constexpr size_t O_PPTR = ZERO_BYTES;                          // NSEG u32 (sort cursor)
constexpr size_t O_LINA = alignup(O_PPTR + (size_t)NSEG * 4);  // NPTS u32 (per-point lin)
constexpr size_t O_ROWI = alignup(O_LINA + (size_t)NPTS * 4);  // NPTS uint4 (rank -> id,start,n)
constexpr size_t O_FEAT = alignup(O_ROWI + (size_t)NPTS * 16); // NPTS*16 f32 (sorted feats)
constexpr size_t O_BSO  = alignup(O_FEAT + (size_t)NPTS * 64); // NB_SCAN u32 occ block sums
constexpr size_t O_BSC  = alignup(O_BSO + NB_SCAN * 4);        // NB_SCAN u32 cnt block sums
constexpr size_t O_KP   = alignup(O_BSC + NB_SCAN * 4);        // 1 u32 (#real pillars)
constexpr size_t O_WF   = alignup(O_KP + 256);                 // 832 f32: W*scale folded
constexpr size_t O_SH   = alignup(O_WF + 832 * 4);             // 64 f32: shift

// binning: mirror reference f32 arithmetic exactly (division, trunc, compares)
__device__ __forceinline__ int point_lin(float x, float y, int b, bool& mask) {
  float cxf = x / 0.2f;
  float cyf = (y + 40.0f) / 0.2f;
  int cx = (int)cxf, cy = (int)cyf;
  mask = (cxf >= 0.0f) && (cxf < 352.0f) && (cyf >= 0.0f) && (cyf < 400.0f);
  return mask ? (b * GXGY + cx * GYv + cy) : SENT;
}

// ---------------- K1: count + xyz sums + lin cache ----------------
__global__ __launch_bounds__(256) void k_count(const float* __restrict__ pts,
                                               unsigned int* __restrict__ cnt,
                                               float* __restrict__ sums,
                                               unsigned int* __restrict__ lina) {
  int i = blockIdx.x * 256 + threadIdx.x;
  if (i >= NPTS) return;
  const float* p = pts + (size_t)i * 7;
  float x = p[0], y = p[1], z = p[2];
  bool m;
  int lin = point_lin(x, y, i >> 16, m);
  lina[i] = (unsigned)lin;
  atomicAdd(&cnt[lin], 1u);
  atomicAdd(&sums[lin * 3 + 0], x);
  atomicAdd(&sums[lin * 3 + 1], y);
  atomicAdd(&sums[lin * 3 + 2], z);
}

// ---------------- K2: per-block occupancy/count sums ----------------
__global__ __launch_bounds__(256) void k_scan1(const unsigned int* __restrict__ cnt,
                                               unsigned int* __restrict__ bso,
                                               unsigned int* __restrict__ bsc) {
  int t = threadIdx.x;
  int base = blockIdx.x * 2048 + t * 8;
  const uint4* c4 = (const uint4*)(cnt + base);
  uint4 a = c4[0], b = c4[1];
  unsigned so = (a.x > 0) + (a.y > 0) + (a.z > 0) + (a.w > 0) +
                (b.x > 0) + (b.y > 0) + (b.z > 0) + (b.w > 0);
  unsigned sc = a.x + a.y + a.z + a.w + b.x + b.y + b.z + b.w;
  for (int m = 1; m < 64; m <<= 1) { so += __shfl_xor(so, m); sc += __shfl_xor(sc, m); }
  __shared__ unsigned wo[4], wc[4];
  if ((t & 63) == 0) { wo[t >> 6] = so; wc[t >> 6] = sc; }
  __syncthreads();
  if (t == 0) {
    bso[blockIdx.x] = wo[0] + wo[1] + wo[2] + wo[3];
    bsc[blockIdx.x] = wc[0] + wc[1] + wc[2] + wc[3];
  }
}

// ---------------- K3: ranks + rowinfo + sort-cursor (self-computed block offsets) ----------------
__global__ __launch_bounds__(256) void k_scan3(const unsigned int* __restrict__ cnt,
                                               const unsigned int* __restrict__ bso,
                                               const unsigned int* __restrict__ bsc,
                                               uint4* __restrict__ rowinfo,
                                               unsigned int* __restrict__ pptr,
                                               unsigned int* __restrict__ kp) {
  int t = threadIdx.x;
  // block offsets: reduce per-block sums below blockIdx.x (and total occ for kp)
  // NB_SCAN (275) > blockDim (256): strided loop covers all entries.
  unsigned vo_m = 0, vc_m = 0, vo_a = 0;
  for (int e = t; e < NB_SCAN; e += 256) {
    unsigned o = bso[e], c = bsc[e];
    vo_a += o;
    if (e < (int)blockIdx.x) { vo_m += o; vc_m += c; }
  }
  for (int m = 1; m < 64; m <<= 1) {
    vo_m += __shfl_xor(vo_m, m);
    vc_m += __shfl_xor(vc_m, m);
    vo_a += __shfl_xor(vo_a, m);
  }
  __shared__ unsigned s0[4], s1[4], s2[4];
  int wv = t >> 6;
  if ((t & 63) == 0) { s0[wv] = vo_m; s1[wv] = vc_m; s2[wv] = vo_a; }
  __syncthreads();
  unsigned boo = s0[0] + s0[1] + s0[2] + s0[3];
  unsigned boc = s1[0] + s1[1] + s1[2] + s1[3];
  unsigned tot = s2[0] + s2[1] + s2[2] + s2[3];
  if (blockIdx.x == 0 && t == 0) *kp = tot;

  int base = blockIdx.x * 2048 + t * 8;
  const uint4* q = (const uint4*)(cnt + base);
  uint4 a = q[0], b = q[1];
  unsigned c[8] = {a.x, a.y, a.z, a.w, b.x, b.y, b.z, b.w};
  unsigned po[8], pc[8];
  unsigned so = 0, sc = 0;
#pragma unroll
  for (int k = 0; k < 8; k++) {
    po[k] = so; pc[k] = sc;
    so += (c[k] > 0); sc += c[k];
  }
  __shared__ unsigned sdo[256], sdc[256];
  __syncthreads();
  sdo[t] = so; sdc[t] = sc;
  __syncthreads();
  for (int off = 1; off < 256; off <<= 1) {
    unsigned ao = (t >= off) ? sdo[t - off] : 0u;
    unsigned ac = (t >= off) ? sdc[t - off] : 0u;
    __syncthreads();
    sdo[t] += ao; sdc[t] += ac;
    __syncthreads();
  }
  unsigned eo = sdo[t] - so + boo;
  unsigned ec = sdc[t] - sc + boc;
#pragma unroll
  for (int k = 0; k < 8; k++) {
    if (c[k] > 0) {
      unsigned r = eo + po[k];
      unsigned start = ec + pc[k];
      rowinfo[r] = make_uint4((unsigned)(base + k), start, c[k], 0u);
      pptr[base + k] = start;   // exclusive start; sortfeat advances to start+n
    }
  }
}

// ---------------- K4: counting-sort + feature materialization ----------------
__global__ __launch_bounds__(256) void k_sortfeat(const float* __restrict__ pts,
                                                  const unsigned int* __restrict__ lina,
                                                  const unsigned int* __restrict__ cnt,
                                                  const float* __restrict__ sums,
                                                  unsigned int* __restrict__ pptr,
                                                  float* __restrict__ feat) {
  int i = blockIdx.x * 256 + threadIdx.x;
  if (i >= NPTS) return;
  unsigned lin = lina[i];
  if (lin == SENT) return;  // masked points never reach output rows
  const float* p = pts + (size_t)i * 7;
  float x = p[0], y = p[1], z = p[2];
  unsigned pos = atomicAdd(&pptr[lin], 1u);
  float cm = fmaxf((float)cnt[lin], 1.0f);
  float m0 = sums[lin * 3 + 0] / cm;
  float m1 = sums[lin * 3 + 1] / cm;
  float m2 = sums[lin * 3 + 2] / cm;
  int cx = (int)(x / 0.2f);
  int cy = (int)((y + 40.0f) / 0.2f);
  int cz = (int)((z + 3.0f) / 4.0f);
  float4 A = make_float4(x, y, z, p[3]);
  float4 B = make_float4(p[4], p[5], p[6], x - m0);
  float4 C = make_float4(y - m1, z - m2,
                         x - ((float)cx * 0.2f + 0.1f + 0.0f),
                         y - ((float)cy * 0.2f + 0.1f - 40.0f));
  float4 D = make_float4(z - ((float)cz * 4.0f + 2.0f - 3.0f), 0.f, 0.f, 0.f);
  float4* fb = (float4*)(feat + (size_t)pos * 16);
  fb[0] = A; fb[1] = B; fb[2] = C; fb[3] = D;
}

// ---------------- K5: feature moments (streams feat array) ----------------
// x = F W^T  =>  mu = W*E[f],  E[x_c^2] = w_c E[f f^T] w_c^T
constexpr int tri_j(int t) { int j = 0; while (t >= 13 - j) { t -= 13 - j; j++; } return j; }
constexpr int tri_k(int t) { int j = 0; while (t >= 13 - j) { t -= 13 - j; j++; } return j + t; }

template<int G, size_t U>
__device__ __forceinline__ void accum_one(const float (&f)[13], float (&acc)[52]) {
  constexpr int E = G * 52 + (int)U;
  if constexpr (E < 13) {
    acc[U] += f[E];
  } else {
    constexpr int J = tri_j(E - 13);
    constexpr int K = tri_k(E - 13);
    acc[U] += f[J] * f[K];
  }
}
template<int G, size_t... Us>
__device__ __forceinline__ void accum_all(const float (&f)[13], float (&acc)[52],
                                          std::index_sequence<Us...>) {
  (accum_one<G, Us>(f, acc), ...);
}

template<int G>
__device__ __forceinline__ void moments_body(const float* __restrict__ feat,
                                             float* __restrict__ mom, int chunk) {
  float acc[52];
#pragma unroll
  for (int u = 0; u < 52; u++) acc[u] = 0.f;
#pragma unroll
  for (int r = 0; r < 4; r++) {
    int i = chunk * 1024 + r * 256 + threadIdx.x;
    const float4* fp = (const float4*)(feat + (size_t)i * 16);
    float4 A = fp[0], B = fp[1], C = fp[2], D = fp[3];
    float f[13] = {A.x, A.y, A.z, A.w, B.x, B.y, B.z, B.w, C.x, C.y, C.z, C.w, D.x};
    accum_all<G>(f, acc, std::make_index_sequence<52>{});
  }
  __shared__ float red[4][52];
  int wv = threadIdx.x >> 6, lane = threadIdx.x & 63;
#pragma unroll
  for (int u = 0; u < 52; u++) {
    float v = acc[u];
    v += __shfl_xor(v, 1);  v += __shfl_xor(v, 2);  v += __shfl_xor(v, 4);
    v += __shfl_xor(v, 8);  v += __shfl_xor(v, 16); v += __shfl_xor(v, 32);
    if (lane == 0) red[wv][u] = v;
  }
  __syncthreads();
  if (threadIdx.x < 52) {
    int u = threadIdx.x;
    atomicAdd(&mom[G * 52 + u], red[0][u] + red[1][u] + red[2][u] + red[3][u]);
  }
}

__global__ __launch_bounds__(256, 2) void k_moments(const float* __restrict__ feat,
                                                    float* __restrict__ mom) {
  int chunk = blockIdx.x >> 1;     // 256 chunks x 1024 points == NPTS exactly
  if ((blockIdx.x & 1) == 0) moments_body<0>(feat, mom, chunk);
  else                       moments_body<1>(feat, mom, chunk);
}

// ---------------- K6: finalize BN; fold scale into W ----------------
__global__ void k_bnfinal(const float* __restrict__ W,
                          const float* __restrict__ g,
                          const float* __restrict__ bta,
                          const float* __restrict__ mom,
                          float* __restrict__ wf,
                          float* __restrict__ sh) {
  int c = threadIdx.x;  // 64 threads
  float w[13];
#pragma unroll
  for (int j = 0; j < 13; j++) w[j] = W[c * 13 + j];
  const float invN = 1.0f / (float)NPTS;
  float mu = 0.f;
#pragma unroll
  for (int j = 0; j < 13; j++) mu += w[j] * (mom[j] * invN);
  float e2 = 0.f;
  int mi = 13;
#pragma unroll
  for (int j = 0; j < 13; j++) {
#pragma unroll
    for (int k = j; k < 13; k++) {
      float coef = (j == k) ? 1.0f : 2.0f;
      e2 += coef * w[j] * w[k] * mom[mi];
      mi++;
    }
  }
  e2 *= invN;
  float var = e2 - mu * mu;
  float rsig = 1.0f / sqrtf(var + 1e-3f);
  float sc = g[c] * rsig;
#pragma unroll
  for (int j = 0; j < 13; j++) wf[c * 13 + j] = w[j] * sc;
  sh[c] = bta[c] - mu * sc;
}

// ---------------- K7: persistent per-pillar PFN + max + full output ----------------
// rowinfo gives (id,start,n) in ONE coalesced load; feat reads are sequential
// in rank order. Weights in 52 VGPRs per lane, loaded once per thread.
__global__ __launch_bounds__(256) void k_pillar(const float* __restrict__ wf,
                                                const float* __restrict__ sh,
                                                const uint4* __restrict__ rowinfo,
                                                const unsigned int* __restrict__ kp_p,
                                                const float* __restrict__ feat,
                                                float* __restrict__ out) {
  int tid = threadIdx.x;
  int lane = tid & 15;
  int ch0 = lane * 4;
  float wr[52];
  float shv[4];
#pragma unroll
  for (int c4 = 0; c4 < 4; c4++) {
    shv[c4] = sh[ch0 + c4];
#pragma unroll
    for (int j = 0; j < 13; j++) wr[c4 * 13 + j] = wf[(ch0 + c4) * 13 + j];
  }
  unsigned kp = *kp_p;

  const int NGRP = PIL_BLOCKS * 16;
  for (int r = blockIdx.x * 16 + (tid >> 4); r < NSEG; r += NGRP) {
    float m0 = -3.4e38f, m1 = -3.4e38f, m2 = -3.4e38f, m3 = -3.4e38f;
    int b = 4, cy = 0, cx = 0;
    if ((unsigned)r < kp) {
      uint4 ri = rowinfo[r];
      unsigned id = ri.x, start = ri.y, n = ri.z;
      b = id / GXGY;
      unsigned rem = id - (unsigned)b * GXGY;
      cx = rem / GYv;
      cy = rem - cx * GYv;
      const float4* fb = (const float4*)(feat + (size_t)start * 16);
      for (unsigned p = 0; p < n; p++) {
        float4 A = fb[0], B = fb[1], C = fb[2], D = fb[3];
        fb += 4;
        float d0, d1, d2, d3;
#define DOT(dst, c4)                                                          \
        dst = shv[c4];                                                        \
        dst += wr[c4 * 13 + 0]  * A.x;  dst += wr[c4 * 13 + 1]  * A.y;        \
        dst += wr[c4 * 13 + 2]  * A.z;  dst += wr[c4 * 13 + 3]  * A.w;        \
        dst += wr[c4 * 13 + 4]  * B.x;  dst += wr[c4 * 13 + 5]  * B.y;        \
        dst += wr[c4 * 13 + 6]  * B.z;  dst += wr[c4 * 13 + 7]  * B.w;        \
        dst += wr[c4 * 13 + 8]  * C.x;  dst += wr[c4 * 13 + 9]  * C.y;        \
        dst += wr[c4 * 13 + 10] * C.z;  dst += wr[c4 * 13 + 11] * C.w;        \
        dst += wr[c4 * 13 + 12] * D.x;
        DOT(d0, 0) DOT(d1, 1) DOT(d2, 2) DOT(d3, 3)
#undef DOT
        m0 = fmaxf(m0, d0); m1 = fmaxf(m1, d1);
        m2 = fmaxf(m2, d2); m3 = fmaxf(m3, d3);
      }
    }
    float4 v = make_float4(fmaxf(m0, 0.f), fmaxf(m1, 0.f),
                           fmaxf(m2, 0.f), fmaxf(m3, 0.f));
    *(float4*)(out + (size_t)r * 64 + lane * 4) = v;
    if (lane == 0) {
      float* cc = out + (size_t)NSEG * 64 + (size_t)r * 3;
      cc[0] = (float)b;
      cc[1] = (float)cy;
      cc[2] = (float)cx;
    }
  }
  if (blockIdx.x == 0 && tid == 0) {
    float* g = out + (size_t)NSEG * 67;
    g[0] = 400.0f;  // GY
    g[1] = 352.0f;  // GX
  }
}

// ---------------- host launcher ----------------
extern "C" void kernel_launch(void* const* d_in, const int* in_sizes, int n_in,
                              void* d_out, int out_size, void* d_ws, size_t ws_size,
                              hipStream_t stream) {
  const float* pts = (const float*)d_in[0];
  const float* W   = (const float*)d_in[1];
  const float* g   = (const float*)d_in[2];
  const float* bta = (const float*)d_in[3];
  float* out = (float*)d_out;
  char* ws = (char*)d_ws;

  unsigned int* cnt  = (unsigned int*)(ws + O_CNT);
  float*        sums = (float*)(ws + O_SUMS);
  float*        mom  = (float*)(ws + O_MOM);
  unsigned int* pptr = (unsigned int*)(ws + O_PPTR);
  unsigned int* lina = (unsigned int*)(ws + O_LINA);
  uint4*        rowi = (uint4*)(ws + O_ROWI);
  float*        feat = (float*)(ws + O_FEAT);
  unsigned int* bso  = (unsigned int*)(ws + O_BSO);
  unsigned int* bsc  = (unsigned int*)(ws + O_BSC);
  unsigned int* kp   = (unsigned int*)(ws + O_KP);
  float*        wf   = (float*)(ws + O_WF);
  float*        sh   = (float*)(ws + O_SH);
  (void)in_sizes; (void)n_in; (void)out_size; (void)ws_size;

  hipMemsetAsync(ws, 0, ZERO_BYTES, stream);   // cnt + sums + moments

  k_count   <<<NPTS / 256, 256, 0, stream>>>(pts, cnt, sums, lina);
  k_scan1   <<<NB_SCAN, 256, 0, stream>>>(cnt, bso, bsc);
  k_scan3   <<<NB_SCAN, 256, 0, stream>>>(cnt, bso, bsc, rowi, pptr, kp);
  k_sortfeat<<<NPTS / 256, 256, 0, stream>>>(pts, lina, cnt, sums, pptr, feat);
  k_moments <<<MOM_BLOCKS, 256, 0, stream>>>(feat, mom);
  k_bnfinal <<<1, 64, 0, stream>>>(W, g, bta, mom, wf, sh);
  k_pillar  <<<PIL_BLOCKS, 256, 0, stream>>>(wf, sh, rowi, kp, feat, out);
}